// Round 6
// baseline (456.419 us; speedup 1.0000x reference)
//
#include <hip/hip_runtime.h>

#define BATCH 8192
#define V 512
#define N1 513
#define KCH 16
#define NCHUNKS 32
#define RB 16            // rows per block -> grid 512 = exactly 2 blocks/CU
#define NT 1024          // 16 waves; each wave owns ONE chain row
#define PKS 520          // Phi row stride (bf16 elems)
#define SJ2 516          // S row stride (dwords): 2-way (free) write conflicts

typedef __bf16 bf16_t;
typedef bf16_t bf16x8 __attribute__((ext_vector_type(8)));
typedef float f32x4 __attribute__((ext_vector_type(4)));

// workspace: Mhi (fragment-linear triangular pack, mat=1 tiles PRE-NEGATED),
// Dv (fp32, pre-scaled by mat sign), Bv (fp32, pre-negated mat=1).
//   chunk cc in 1..31: nkb = ceil(cc/2) k-blocks of 32 (zero-pad past 16*cc);
//   base elems = 16384*floor(cc^2/4); elem = base + (kb*32 + t)*512 + lane*8 + jj
//   with t = j-tile index, lane = c + 16*q, k = kb*32 + 8*q + jj.
// Dv: [cc][vl][512 j], j = 32*vlo + 16*mat + c. Bv: [cc][512 j].
#define EPP 4194304ull
#define DV_OFF (EPP * 2ull)
#define BV_OFF (DV_OFF + 1048576ull)

__device__ __forceinline__ f32x4 mfma16(bf16x8 a, bf16x8 b, f32x4 c) {
    return __builtin_amdgcn_mfma_f32_16x16x32_bf16(a, b, c, 0, 0, 0);
}

__device__ __forceinline__ float bcast_lane(float x, int l) {
    return __int_as_float(__builtin_amdgcn_readlane(__float_as_int(x), l));
}

__device__ __forceinline__ float dpp_xor1_max(float x) {
    const int xi = __float_as_int(x);
    // quad_perm [1,0,3,2] = 0xB1 -> swap xor-1 neighbours, no DS op
    const float o = __int_as_float(
        __builtin_amdgcn_update_dpp(xi, xi, 0xB1, 0xF, 0xF, false));
    return fmaxf(x, o);
}

// ---- unified repack (unchanged from R5): 1024 threads/block; Mhi output
// vectorized to bf16x8 stores via 16B-aligned LDS reads (row stride 36).
// Blocks 0..495 pack Mhi; 496..527 pack Dv/Bv (stride-17 views). -----------
__global__ __launch_bounds__(1024)
void repack_all(const float* __restrict__ pos, const float* __restrict__ neg,
                bf16_t* __restrict__ Mhi, float* __restrict__ Dv,
                float* __restrict__ Bv)
{
    __shared__ float sb[2 * 256 * 36];   // 73,728 B
    const int bx  = blockIdx.x;
    const int tid = threadIdx.x;
    if (bx < 496) {
        const int cc  = (bx >> 4) + 1;       // 1..31
        const int kb  = bx & 15;
        const int nkb = (cc + 1) >> 1;
        if (kb >= nkb) return;
        const int klen = 16 * cc;
        for (int idx = tid; idx < 8192; idx += 1024) {
            const int r = idx >> 5, k32 = idx & 31;
            const int k = kb * 32 + k32;
            const size_t row = (size_t)cc * 256 + r;
            float xp = 0.0f, xn = 0.0f;
            if (k < klen) {
                xp = pos[row * N1 + k];
                xn = -neg[row * N1 + k];     // pre-negate mat=1
            }
            sb[r * 36 + k32]            = xp;
            sb[256 * 36 + r * 36 + k32] = xn;
        }
        __syncthreads();
        const size_t base = 16384ull * (size_t)((cc * cc) / 4) + (size_t)kb * 16384ull;
        for (int e8 = tid; e8 < 2048; e8 += 1024) {
            const int t = e8 >> 6, s = e8 & 63;
            const int c = s & 15, q = s >> 4;
            const int vloc = t >> 1, m = t & 1;
            const float* sp = &sb[m * 256 * 36 + (vloc * 16 + c) * 36 + 8 * q];
            bf16x8 o;
            #pragma unroll
            for (int jj = 0; jj < 8; ++jj) o[jj] = (bf16_t)sp[jj];
            *(bf16x8*)(Mhi + base + (size_t)e8 * 8) = o;
        }
    } else {
        const int cc = bx - 496;             // 0..31, one block per chunk
        float* bufP = sb;                    // stride-17 views
        float* bufN = sb + 256 * 17;
        for (int idx = tid; idx < 4096; idx += 1024) {
            const int r = idx >> 4, kk = idx & 15;
            const size_t row = (size_t)(cc * 256 + r);
            bufP[r * 17 + kk] = pos[row * N1 + cc * 16 + kk];
            bufN[r * 17 + kk] = neg[row * N1 + cc * 16 + kk];
        }
        __syncthreads();
        for (int idx = tid; idx < 8192; idx += 1024) {
            const int vl = idx >> 9, j = idx & 511;
            const int vlo = j >> 5, c = j & 15;
            const int m = (j >> 4) & 1;
            const float x = (m ? bufN : bufP)[(vlo * 16 + c) * 17 + vl];
            Dv[(size_t)cc * 8192 + idx] = m ? -x : x;
        }
        for (int j = tid; j < 512; j += 1024) {
            const int vlo = j >> 5, c = j & 15;
            const int m = (j >> 4) & 1;
            const float* src = m ? neg : pos;
            const float x = src[(size_t)(cc * 256 + vlo * 16 + c) * N1 + V];
            Bv[(size_t)cc * 512 + j] = m ? -x : x;
        }
    }
}

// ---- fused main kernel R6: 16 rows, 16 waves, ONE row per wave, grid 512 ------
// The R1 structure was latency-bound at a STRUCTURAL 16 waves/CU (1 wave per 2
// batch rows = 4096 waves; issue occupancy ~20%). R6 halves rows-per-wave:
// wave w owns chain row w; GEMM j-tiles 2w..2w+1 (rows 0..15, acc[2]); grid
// 512 = 2 blocks/CU -> 32 waves/CU (8/SIMD) IF total regs <= 64/wave. The
// one-row diet makes that possible: s2 8 (was 16), po prefetch dropped
// (per-step broadcast ds_read_u16), acc 8 AGPR (was 16), fb 8. LDS 49,664 B
// (2x49.7 = 99 KB <= 160). launch_bounds(NT,8) pins the 64-reg budget.
// Numerics bit-identical per row (same fmax/fma/MFMA order) -> absmax 8.0.
// Spill tell: WRITE_SIZE >> 18.4 MB means the 64-budget didn't fit.
__global__ __launch_bounds__(NT, 8)
void shield_fused(const float* __restrict__ preds,
                  const bf16_t* __restrict__ Mhi,
                  const float* __restrict__ Dv, const float* __restrict__ Bv,
                  float* __restrict__ out)
{
    __shared__ bf16_t Phi[RB * PKS];   // 16,640 B
    __shared__ float  S[RB * SJ2];     // 33,024 B  (total 49,664 -> 2 blocks/CU)

    const int tid  = threadIdx.x;
    const int b0   = blockIdx.x * RB;
    const int lane = tid & 63;
    const int w    = tid >> 6;          // 0..15; chain row = w
    const int cq   = lane & 15;
    const int q    = lane >> 4;

    // ---- load preds -> Phi: wave w loads its row, 8 cols/lane, coalesced ----
    {
        const float* prow = preds + (size_t)(b0 + w) * V + lane * 8;
        const float4 p0 = *(const float4*)(prow);
        const float4 p1 = *(const float4*)(prow + 4);
        const int n = lane * 8;
        Phi[w * PKS + n + 0] = (bf16_t)p0.x;
        Phi[w * PKS + n + 1] = (bf16_t)p0.y;
        Phi[w * PKS + n + 2] = (bf16_t)p0.z;
        Phi[w * PKS + n + 3] = (bf16_t)p0.w;
        Phi[w * PKS + n + 4] = (bf16_t)p1.x;
        Phi[w * PKS + n + 5] = (bf16_t)p1.y;
        Phi[w * PKS + n + 6] = (bf16_t)p1.z;
        Phi[w * PKS + n + 7] = (bf16_t)p1.w;
    }

    int tJ[2];
    #pragma unroll
    for (int tt = 0; tt < 2; ++tt) tJ[tt] = ((2 * w + tt) << 4) + cq;
    const int aoff = cq * PKS + 8 * q;

    // acc(0) = bias(0)
    f32x4 acc[2];
    #pragma unroll
    for (int tt = 0; tt < 2; ++tt) {
        const float b = Bv[tJ[tt]];
        acc[tt] = f32x4{b, b, b, b};
    }

    #pragma unroll 1
    for (int cc = 0; cc < NCHUNKS; ++cc) {
        const int v0 = cc * 16;
        const int  ccn  = cc + 1;
        const bool hasN = ccn < NCHUNKS;
        const int  nkbN = hasN ? ((ccn + 1) >> 1) : 0;
        const bf16_t* phN = Mhi + 16384ull * (size_t)((ccn * ccn) / 4)
                          + (size_t)lane * 8 + (size_t)(2 * w) * 512;

        // ---- dump acc(cc) -> S ----
        #pragma unroll
        for (int tt = 0; tt < 2; ++tt)
            #pragma unroll
            for (int reg = 0; reg < 4; ++reg)
                S[(4 * q + reg) * SJ2 + tJ[tt]] = acc[tt][reg];
        __syncthreads();   // (A) S ready; prior Phi writes visible

        // ---- load s2: lane owns j = 8*lane..8*lane+7 of row w ----
        // (16-phase read, but only once per chunk -> negligible)
        float s2[8];
        {
            const float* sp = &S[w * SJ2 + 8 * lane];
            const float4 a0 = *(const float4*)(sp);
            const float4 a1 = *(const float4*)(sp + 4);
            s2[0] = a0.x; s2[1] = a0.y; s2[2] = a0.z; s2[3] = a0.w;
            s2[4] = a1.x; s2[5] = a1.y; s2[6] = a1.z; s2[7] = a1.w;
        }

        // ---- init acc(ccn) with bias ----
        if (hasN) {
            #pragma unroll
            for (int tt = 0; tt < 2; ++tt) {
                const float b = Bv[(ccn << 9) + tJ[tt]];
                acc[tt] = f32x4{b, b, b, b};
            }
        }

        // ---- 16-step serial chain + interleaved bulk GEMM of chunk ccn ----
        #pragma unroll
        for (int vl = 0; vl < KCH; ++vl) {
            const int vcur = v0 + vl;
            const bool doKb = hasN && (vl < nkbN - 1);

            bf16x8 fa, fb0, fb1;
            if (doKb) {
                const int k0 = vl * 32;
                fa  = *(const bf16x8*)(Phi + aoff + k0);
                const bf16_t* pb = phN + (size_t)k0 * 512;
                fb0 = *(const bf16x8*)(pb);
                fb1 = *(const bf16x8*)(pb + 512);
            }

            // this step's dv (global, L1/L2-hot); consumed post-reduce
            float dv[8];
            {
                const float* dp = Dv + ((size_t)vcur << 9) + 8 * lane;
                const float4 d0 = *(const float4*)(dp);
                const float4 d1 = *(const float4*)(dp + 4);
                dv[0]=d0.x; dv[1]=d0.y; dv[2]=d0.z; dv[3]=d0.w;
                dv[4]=d1.x; dv[5]=d1.y; dv[6]=d1.z; dv[7]=d1.w;
            }
            // po: broadcast LDS read (all lanes same addr, no conflict).
            // Read-before-write of the same location is same-wave program order.
            const float po = (float)Phi[w * PKS + vcur];

            // in-lane reduce 8 -> 1 (max3-fusable), xor-1 merge via DPP
            const float m0 = fmaxf(fmaxf(s2[0], s2[1]), s2[2]);
            const float m1 = fmaxf(fmaxf(s2[3], s2[4]), s2[5]);
            const float m2 = fmaxf(s2[6], s2[7]);
            const float red = dpp_xor1_max(fmaxf(fmaxf(m0, m1), m2));
            // broadcast from compile-time lanes via v_readlane (no DS op)
            const float lw  = bcast_lane(red, 4 * vl);       // lower
            const float nup = bcast_lane(red, 4 * vl + 2);   // -upper
            const float pc  = fminf(fmaxf(po, lw), -nup);
            if (lane == 4 * vl) Phi[w * PKS + vcur] = (bf16_t)pc;

            // rank-1 update (Dv pre-scaled so no sign mul)
            #pragma unroll
            for (int jj = 0; jj < 8; ++jj) s2[jj] = fmaf(dv[jj], pc, s2[jj]);

            if (doKb) {
                acc[0] = mfma16(fa, fb0, acc[0]);
                acc[1] = mfma16(fa, fb1, acc[1]);
            }
        }

        __syncthreads();   // (D) fresh Phi columns visible; S safe to reuse

        // ---- final k-block of chunk ccn (zero-padded B -> exact no-ops) ----
        if (hasN) {
            const int k0 = (nkbN - 1) * 32;
            const bf16x8 fa  = *(const bf16x8*)(Phi + aoff + k0);
            const bf16_t* pb = phN + (size_t)k0 * 512;
            const bf16x8 fb0 = *(const bf16x8*)(pb);
            const bf16x8 fb1 = *(const bf16x8*)(pb + 512);
            acc[0] = mfma16(fa, fb0, acc[0]);
            acc[1] = mfma16(fa, fb1, acc[1]);
        }
    }

    // ---- epilogue: wave w writes its row, 8 cols/lane, coalesced ----
    {
        float* orow = out + (size_t)(b0 + w) * V + lane * 8;
        const int n = lane * 8;
        float4 o0, o1;
        o0.x = (float)Phi[w * PKS + n + 0];
        o0.y = (float)Phi[w * PKS + n + 1];
        o0.z = (float)Phi[w * PKS + n + 2];
        o0.w = (float)Phi[w * PKS + n + 3];
        o1.x = (float)Phi[w * PKS + n + 4];
        o1.y = (float)Phi[w * PKS + n + 5];
        o1.z = (float)Phi[w * PKS + n + 6];
        o1.w = (float)Phi[w * PKS + n + 7];
        *(float4*)(orow)     = o0;
        *(float4*)(orow + 4) = o1;
    }
}

extern "C" void kernel_launch(void* const* d_in, const int* in_sizes, int n_in,
                              void* d_out, int out_size, void* d_ws, size_t ws_size,
                              hipStream_t stream) {
    const float* preds = (const float*)d_in[0];
    const float* pos   = (const float*)d_in[1];
    const float* neg   = (const float*)d_in[2];
    float* o = (float*)d_out;
    char* base = (char*)d_ws;
    bf16_t* Mhi = (bf16_t*)base;
    float*  Dv  = (float*)(base + DV_OFF);
    float*  Bv  = (float*)(base + BV_OFF);
    repack_all<<<dim3(528), 1024, 0, stream>>>(pos, neg, Mhi, Dv, Bv);
    shield_fused<<<dim3(BATCH / RB), NT, 0, stream>>>(preds, Mhi, Dv, Bv, o);
}

// Round 7
// 356.501 us; speedup vs baseline: 1.2803x; 1.2803x over previous
//
#include <hip/hip_runtime.h>

#define BATCH 8192
#define V 512
#define N1 513
#define KCH 16
#define NCHUNKS 32
#define RB 16            // rows per block -> grid 512 = 2 blocks/CU, 32 waves/CU
#define NT 1024          // 16 waves; each wave owns ONE chain row
#define PKS 520          // Phi row stride (bf16 elems)
#define SJ2 516          // S row stride (dwords)

typedef __bf16 bf16_t;
typedef bf16_t bf16x8 __attribute__((ext_vector_type(8)));
typedef float f32x4 __attribute__((ext_vector_type(4)));

// workspace: Mhi (fragment-linear triangular pack, mat=1 tiles PRE-NEGATED),
// Dv (fp32, pre-scaled by mat sign), Bv (fp32, pre-negated mat=1).
#define EPP 4194304ull
#define DV_OFF (EPP * 2ull)
#define BV_OFF (DV_OFF + 1048576ull)

__device__ __forceinline__ f32x4 mfma16(bf16x8 a, bf16x8 b, f32x4 c) {
    return __builtin_amdgcn_mfma_f32_16x16x32_bf16(a, b, c, 0, 0, 0);
}

__device__ __forceinline__ float bcast_lane(float x, int l) {
    return __int_as_float(__builtin_amdgcn_readlane(__float_as_int(x), l));
}

__device__ __forceinline__ float dpp_xor1_max(float x) {
    const int xi = __float_as_int(x);
    const float o = __int_as_float(
        __builtin_amdgcn_update_dpp(xi, xi, 0xB1, 0xF, 0xF, false));
    return fmaxf(x, o);
}

// ---- unified repack (unchanged from R5) -----------------------------------
__global__ __launch_bounds__(1024)
void repack_all(const float* __restrict__ pos, const float* __restrict__ neg,
                bf16_t* __restrict__ Mhi, float* __restrict__ Dv,
                float* __restrict__ Bv)
{
    __shared__ float sb[2 * 256 * 36];   // 73,728 B
    const int bx  = blockIdx.x;
    const int tid = threadIdx.x;
    if (bx < 496) {
        const int cc  = (bx >> 4) + 1;       // 1..31
        const int kb  = bx & 15;
        const int nkb = (cc + 1) >> 1;
        if (kb >= nkb) return;
        const int klen = 16 * cc;
        for (int idx = tid; idx < 8192; idx += 1024) {
            const int r = idx >> 5, k32 = idx & 31;
            const int k = kb * 32 + k32;
            const size_t row = (size_t)cc * 256 + r;
            float xp = 0.0f, xn = 0.0f;
            if (k < klen) {
                xp = pos[row * N1 + k];
                xn = -neg[row * N1 + k];     // pre-negate mat=1
            }
            sb[r * 36 + k32]            = xp;
            sb[256 * 36 + r * 36 + k32] = xn;
        }
        __syncthreads();
        const size_t base = 16384ull * (size_t)((cc * cc) / 4) + (size_t)kb * 16384ull;
        for (int e8 = tid; e8 < 2048; e8 += 1024) {
            const int t = e8 >> 6, s = e8 & 63;
            const int c = s & 15, q = s >> 4;
            const int vloc = t >> 1, m = t & 1;
            const float* sp = &sb[m * 256 * 36 + (vloc * 16 + c) * 36 + 8 * q];
            bf16x8 o;
            #pragma unroll
            for (int jj = 0; jj < 8; ++jj) o[jj] = (bf16_t)sp[jj];
            *(bf16x8*)(Mhi + base + (size_t)e8 * 8) = o;
        }
    } else {
        const int cc = bx - 496;             // 0..31, one block per chunk
        float* bufP = sb;                    // stride-17 views
        float* bufN = sb + 256 * 17;
        for (int idx = tid; idx < 4096; idx += 1024) {
            const int r = idx >> 4, kk = idx & 15;
            const size_t row = (size_t)(cc * 256 + r);
            bufP[r * 17 + kk] = pos[row * N1 + cc * 16 + kk];
            bufN[r * 17 + kk] = neg[row * N1 + cc * 16 + kk];
        }
        __syncthreads();
        for (int idx = tid; idx < 8192; idx += 1024) {
            const int vl = idx >> 9, j = idx & 511;
            const int vlo = j >> 5, c = j & 15;
            const int m = (j >> 4) & 1;
            const float x = (m ? bufN : bufP)[(vlo * 16 + c) * 17 + vl];
            Dv[(size_t)cc * 8192 + idx] = m ? -x : x;
        }
        for (int j = tid; j < 512; j += 1024) {
            const int vlo = j >> 5, c = j & 15;
            const int m = (j >> 4) & 1;
            const float* src = m ? neg : pos;
            const float x = src[(size_t)(cc * 256 + vlo * 16 + c) * N1 + V];
            Bv[(size_t)cc * 512 + j] = m ? -x : x;
        }
    }
}

// ---- fused main kernel R7: R6 geometry (16 rows, 1 row/wave, 2 blocks/CU) ----
// R6 was L1-throughput-bound: 32 waves/CU x (2KB Dv + 2KB fb)/step = 128KB per
// step-window vs ~64B/cy L1 ceiling. Dv is IDENTICAL across the 16 waves of a
// block -> stage the chunk's 16x512 Dv slab into LDS once per chunk (wave w
// stages row w, coalesced 2KB). No spare LDS at 2 blocks/CU, so Dv aliases the
// S region, which is dead after the s2 load: per chunk
//   dump->S, bar A, s2-load + po-prefetch, bar B, stage Dv->S, bar C,
//   16-step chain (dv from LDS), bar D, final k-block.
// po restored to register prefetch (R1's proven pattern) - removes the
// dependent LDS read from the serial chain's critical path.
// Register budget at (NT,8): 64 total/wave; arch ~48 + acc 8 AGPR fits.
// Spill tell: WRITE_SIZE >> 16.4 MB.
__global__ __launch_bounds__(NT, 8)
void shield_fused(const float* __restrict__ preds,
                  const bf16_t* __restrict__ Mhi,
                  const float* __restrict__ Dv, const float* __restrict__ Bv,
                  float* __restrict__ out)
{
    __shared__ bf16_t Phi[RB * PKS];   // 16,640 B
    __shared__ float  S[RB * SJ2];     // 33,024 B; aliased as Dv_lds[16][512]
                                       // total 49,664 -> 2 blocks/CU

    const int tid  = threadIdx.x;
    const int b0   = blockIdx.x * RB;
    const int lane = tid & 63;
    const int w    = tid >> 6;          // 0..15; chain row = w
    const int cq   = lane & 15;
    const int q    = lane >> 4;

    // ---- load preds -> Phi: wave w loads its row, 8 cols/lane, coalesced ----
    {
        const float* prow = preds + (size_t)(b0 + w) * V + lane * 8;
        const float4 p0 = *(const float4*)(prow);
        const float4 p1 = *(const float4*)(prow + 4);
        const int n = lane * 8;
        Phi[w * PKS + n + 0] = (bf16_t)p0.x;
        Phi[w * PKS + n + 1] = (bf16_t)p0.y;
        Phi[w * PKS + n + 2] = (bf16_t)p0.z;
        Phi[w * PKS + n + 3] = (bf16_t)p0.w;
        Phi[w * PKS + n + 4] = (bf16_t)p1.x;
        Phi[w * PKS + n + 5] = (bf16_t)p1.y;
        Phi[w * PKS + n + 6] = (bf16_t)p1.z;
        Phi[w * PKS + n + 7] = (bf16_t)p1.w;
    }

    int tJ[2];
    #pragma unroll
    for (int tt = 0; tt < 2; ++tt) tJ[tt] = ((2 * w + tt) << 4) + cq;
    const int aoff = cq * PKS + 8 * q;

    // acc(0) = bias(0)
    f32x4 acc[2];
    #pragma unroll
    for (int tt = 0; tt < 2; ++tt) {
        const float b = Bv[tJ[tt]];
        acc[tt] = f32x4{b, b, b, b};
    }

    #pragma unroll 1
    for (int cc = 0; cc < NCHUNKS; ++cc) {
        const int v0 = cc * 16;
        const int  ccn  = cc + 1;
        const bool hasN = ccn < NCHUNKS;
        const int  nkbN = hasN ? ((ccn + 1) >> 1) : 0;
        const bf16_t* phN = Mhi + 16384ull * (size_t)((ccn * ccn) / 4)
                          + (size_t)lane * 8 + (size_t)(2 * w) * 512;

        // ---- dump acc(cc) -> S ----
        #pragma unroll
        for (int tt = 0; tt < 2; ++tt)
            #pragma unroll
            for (int reg = 0; reg < 4; ++reg)
                S[(4 * q + reg) * SJ2 + tJ[tt]] = acc[tt][reg];
        __syncthreads();   // (A) S ready; prior Phi writes visible

        // ---- load s2: lane owns j = 8*lane..8*lane+7 of row w ----
        float s2[8];
        {
            const float* sp = &S[w * SJ2 + 8 * lane];
            const float4 a0 = *(const float4*)(sp);
            const float4 a1 = *(const float4*)(sp + 4);
            s2[0] = a0.x; s2[1] = a0.y; s2[2] = a0.z; s2[3] = a0.w;
            s2[4] = a1.x; s2[5] = a1.y; s2[6] = a1.z; s2[7] = a1.w;
        }

        // ---- po prefetch: cols v0..v0+15 of row w (each col read only at
        // its own step; the correcting write is by this same wave) ----
        const bf16x8 po0 = *(const bf16x8*)(Phi + w * PKS + v0);
        const bf16x8 po1 = *(const bf16x8*)(Phi + w * PKS + v0 + 8);

        // ---- init acc(ccn) with bias ----
        if (hasN) {
            #pragma unroll
            for (int tt = 0; tt < 2; ++tt) {
                const float b = Bv[(ccn << 9) + tJ[tt]];
                acc[tt] = f32x4{b, b, b, b};
            }
        }

        __syncthreads();   // (B) all s2 reads done; S region reusable

        // ---- stage Dv(cc) into the dead S region: wave w stages row w ----
        {
            const float* src = Dv + (((size_t)cc * 16 + w) << 9) + 8 * lane;
            const float4 a = *(const float4*)(src);
            const float4 b = *(const float4*)(src + 4);
            float* dst = S + w * 512 + 8 * lane;
            *(float4*)(dst)     = a;
            *(float4*)(dst + 4) = b;
        }
        __syncthreads();   // (C) Dv_lds ready

        // ---- 16-step serial chain + interleaved bulk GEMM of chunk ccn ----
        #pragma unroll
        for (int vl = 0; vl < KCH; ++vl) {
            const int vcur = v0 + vl;
            const bool doKb = hasN && (vl < nkbN - 1);

            bf16x8 fa, fb0, fb1;
            if (doKb) {
                const int k0 = vl * 32;
                fa  = *(const bf16x8*)(Phi + aoff + k0);
                const bf16_t* pb = phN + (size_t)k0 * 512;
                fb0 = *(const bf16x8*)(pb);
                fb1 = *(const bf16x8*)(pb + 512);
            }

            // this step's dv from LDS (shared across all 16 waves)
            float dv[8];
            {
                const float* dls = S + vl * 512 + 8 * lane;
                const float4 d0 = *(const float4*)(dls);
                const float4 d1 = *(const float4*)(dls + 4);
                dv[0]=d0.x; dv[1]=d0.y; dv[2]=d0.z; dv[3]=d0.w;
                dv[4]=d1.x; dv[5]=d1.y; dv[6]=d1.z; dv[7]=d1.w;
            }
            const float po = (float)(vl < 8 ? po0[vl & 7] : po1[vl & 7]);

            // in-lane reduce 8 -> 1 (max3-fusable), xor-1 merge via DPP
            const float m0 = fmaxf(fmaxf(s2[0], s2[1]), s2[2]);
            const float m1 = fmaxf(fmaxf(s2[3], s2[4]), s2[5]);
            const float m2 = fmaxf(s2[6], s2[7]);
            const float red = dpp_xor1_max(fmaxf(fmaxf(m0, m1), m2));
            // broadcast from compile-time lanes via v_readlane (no DS op)
            const float lw  = bcast_lane(red, 4 * vl);       // lower
            const float nup = bcast_lane(red, 4 * vl + 2);   // -upper
            const float pc  = fminf(fmaxf(po, lw), -nup);
            if (lane == 4 * vl) Phi[w * PKS + vcur] = (bf16_t)pc;

            // rank-1 update (Dv pre-scaled so no sign mul)
            #pragma unroll
            for (int jj = 0; jj < 8; ++jj) s2[jj] = fmaf(dv[jj], pc, s2[jj]);

            if (doKb) {
                acc[0] = mfma16(fa, fb0, acc[0]);
                acc[1] = mfma16(fa, fb1, acc[1]);
            }
        }

        __syncthreads();   // (D) fresh Phi visible; S safe for next dump

        // ---- final k-block of chunk ccn (zero-padded B -> exact no-ops) ----
        if (hasN) {
            const int k0 = (nkbN - 1) * 32;
            const bf16x8 fa  = *(const bf16x8*)(Phi + aoff + k0);
            const bf16_t* pb = phN + (size_t)k0 * 512;
            const bf16x8 fb0 = *(const bf16x8*)(pb);
            const bf16x8 fb1 = *(const bf16x8*)(pb + 512);
            acc[0] = mfma16(fa, fb0, acc[0]);
            acc[1] = mfma16(fa, fb1, acc[1]);
        }
    }

    // ---- epilogue: wave w writes its row, 8 cols/lane, coalesced ----
    {
        float* orow = out + (size_t)(b0 + w) * V + lane * 8;
        const int n = lane * 8;
        float4 o0, o1;
        o0.x = (float)Phi[w * PKS + n + 0];
        o0.y = (float)Phi[w * PKS + n + 1];
        o0.z = (float)Phi[w * PKS + n + 2];
        o0.w = (float)Phi[w * PKS + n + 3];
        o1.x = (float)Phi[w * PKS + n + 4];
        o1.y = (float)Phi[w * PKS + n + 5];
        o1.z = (float)Phi[w * PKS + n + 6];
        o1.w = (float)Phi[w * PKS + n + 7];
        *(float4*)(orow)     = o0;
        *(float4*)(orow + 4) = o1;
    }
}

extern "C" void kernel_launch(void* const* d_in, const int* in_sizes, int n_in,
                              void* d_out, int out_size, void* d_ws, size_t ws_size,
                              hipStream_t stream) {
    const float* preds = (const float*)d_in[0];
    const float* pos   = (const float*)d_in[1];
    const float* neg   = (const float*)d_in[2];
    float* o = (float*)d_out;
    char* base = (char*)d_ws;
    bf16_t* Mhi = (bf16_t*)base;
    float*  Dv  = (float*)(base + DV_OFF);
    float*  Bv  = (float*)(base + BV_OFF);
    repack_all<<<dim3(528), 1024, 0, stream>>>(pos, neg, Mhi, Dv, Bv);
    shield_fused<<<dim3(BATCH / RB), NT, 0, stream>>>(preds, Mhi, Dv, Bv, o);
}